// Round 1
// baseline (2423.682 us; speedup 1.0000x reference)
//
#include <hip/hip_runtime.h>

#define T_STEPS 10000
#define BATCH   512

__device__ __forceinline__ float fexp2(float x) {
#if __has_builtin(__builtin_amdgcn_exp2f)
  return __builtin_amdgcn_exp2f(x);
#else
  return exp2f(x);
#endif
}

__device__ __forceinline__ float frcp(float x) {
#if __has_builtin(__builtin_amdgcn_rcpf)
  return __builtin_amdgcn_rcpf(x);
#else
  return 1.0f / x;
#endif
}

// Quad-local permute: lane j of each quad receives from lane sel_j.
// CTRL = sel0 | sel1<<2 | sel2<<4 | sel3<<6 (DPP quad_perm encoding).
template <int CTRL>
__device__ __forceinline__ float qperm(float v) {
  int i = __builtin_bit_cast(int, v);
#if __has_builtin(__builtin_amdgcn_mov_dpp)
  int r = __builtin_amdgcn_mov_dpp(i, CTRL, 0xF, 0xF, true);
#else
  int r = __builtin_amdgcn_ds_swizzle(i, 0x8000 | CTRL);
#endif
  return __builtin_bit_cast(float, r);
}

// Roles within a quad (element b = tid>>2, role = tid&3):
//   role0: s0=f_W, s1=c_W     role1: s0=f_N, s1=c_N
//   role2: s0=f_R, s1=c_R     role3: s0=h,   s1=dummy
// Per stage, two quad broadcasts of stage-start values:
//   shfl1 (sel [1,0,0,0]) of M1=s1        : r0<-cN, r1<-cW, r2<-cW, r3<-cW(unused)
//   shfl2 (sel [2,3,1,0]) of M2=sel(s0,s1): r0<-cR, r1<-h,  r2<-cN, r3<-fW
// Unified update: r = rcp(1+exp2(W1*xA + W2*xB + W3*s1 + NB));
//   K = (pa*s0+pb)*r + (qa*s0+qb);  s0' = f0 + a*K        (tanh = 1-2r folded)
//   c-chain: r2 = rcp(1+exp2(cs*s0')); Kc = 2*ia*r2 + (ia*s1+ib); s1' = c0 + a*Kc
__global__ __launch_bounds__(64, 1)
void sleep_rk4_kernel(const float* __restrict__ noise,
                      const float* __restrict__ pgRRe,
                      const float* __restrict__ pgRWe,
                      const float* __restrict__ pgWNi,
                      const float* __restrict__ pgWRi,
                      const float* __restrict__ pgNRi,
                      const float* __restrict__ pgNWi,
                      float* __restrict__ out)
{
  const int tid  = (int)(blockIdx.x * 64u + threadIdx.x);
  const int b    = tid >> 2;
  const int role = tid & 3;

  const float g_RRe = *pgRRe, g_RWe = *pgRWe, g_WNi = *pgWNi;
  const float g_WRi = *pgWRi, g_NRi = *pgNRi, g_NWi = *pgNWi;

  const float L2E = 1.4426950408889634f;  // log2(e)

  float W1, W2, W3, NSC, BB, qa, qb, pa, pb, cs, ia, ib;
  float s0, s1;
  int v0i, v1i;
  bool m2sel, dostore1;

  if (role == 0) {              // f_W / c_W   (beta_W=-0.4, alpha_W=0.5, tau_W=1.5e6)
    const float SC = 2.0f * L2E / 0.5f;
    W1 = SC * g_NWi; W2 = SC * g_RWe; W3 = 0.0f; NSC = SC; BB = SC * 0.4f;
    qa = -1.0f / 1.5e6f; qb = 6.5f / 1.5e6f; pa = 0.0f; pb = -6.5f / 1.5e6f;
    cs = 2.0f * L2E / 5.0f; ia = -1.0f / 2.5e4f; ib = 1.0f / 2.5e4f;
    s0 = 6.0f; s1 = 0.9f; v0i = 0; v1i = 3; m2sel = true;  dostore1 = true;
  } else if (role == 1) {       // f_N / c_N   (kappa*h inside arg, alpha_N=0.175, tau_N=6e5)
    const float SC = 2.0f * L2E / 0.175f;
    W1 = SC * g_WNi; W2 = SC * 1.5f; W3 = 0.0f; NSC = SC; BB = 0.0f;
    qa = -1.0f / 6.0e5f; qb = 5.0f / 6.0e5f; pa = 0.0f; pb = -5.0f / 6.0e5f;
    cs = 2.0f * L2E / 4.0f; ia = -1.0f / 1.0e4f; ib = 1.0f / 1.0e4f;
    s0 = 1.0e-3f; s1 = 1.0e-3f; v0i = 1; v1i = 4; m2sel = false; dostore1 = true;
  } else if (role == 2) {       // f_R / c_R   (beta_R=-0.9, alpha_R=0.13, tau_R=6e4)
    const float SC = 2.0f * L2E / 0.13f;
    W1 = SC * g_WRi; W2 = SC * g_NRi; W3 = SC * g_RRe; NSC = SC; BB = SC * 0.9f;
    qa = -1.0f / 6.0e4f; qb = 5.0f / 6.0e4f; pa = 0.0f; pb = -5.0f / 6.0e4f;
    cs = 2.0f * L2E / 2.0f; ia = -1.0f / 1.0e4f; ib = 1.0f / 1.0e4f;
    s0 = 1.0e-3f; s1 = 1.0e-3f; v0i = 2; v1i = 5; m2sel = false; dostore1 = true;
  } else {                      // h (sigmoid in same r-form; dummy c-chain)
    W1 = 0.0f; W2 = -5.0f * L2E; W3 = 0.0f; NSC = 0.0f; BB = 10.0f * L2E; // +5*log2e*theta_W
    qa = -1.0f / 3.06e7f; qb = 0.0f;                     // Q = -h/tau_HS
    pa = (1.0f / 3.06e7f - 1.0f / 3.483e7f);             // P = u = H/tau_HW + h*(1/tHS-1/tHW)
    pb = 1.0f / 3.483e7f;
    cs = 0.0f; ia = 0.0f; ib = 0.0f;
    s0 = 0.5f; s1 = 0.0f; v0i = 6; v1i = 0; m2sel = true;  dostore1 = false;
  }
  const float m2c = 2.0f * ia;
  float f0 = s0, c0 = s1;

  const float* nptr = noise + b;
  float* p0 = out + v0i * BATCH + b;
  float* p1 = out + v1i * BATCH + b;

  // 8-deep register prefetch of per-step noise (fully unrolled -> static regs)
  float nb[8];
#pragma unroll
  for (int j = 0; j < 8; ++j) nb[j] = nptr[j * BATCH];

  const float R6 = 0.16666666666666666f;

  for (int t = 0; t < T_STEPS; t += 8) {
#pragma unroll
    for (int j = 0; j < 8; ++j) {
      const float no = nb[j];
      int tn = t + 8 + j;
      tn = (tn < T_STEPS) ? tn : (T_STEPS - 1);
      nb[j] = nptr[tn * BATCH];

      const float NB = fmaf(NSC, no, BB);
      float acc0 = -3.0f * f0;   // reference comb: (-3v0+2v1+4v2+2v3+v4)/6
      float acc1 = -3.0f * c0;

      auto stage = [&](float a, float cf) {
        const float M1 = s1;
        const float M2 = m2sel ? s0 : s1;
        const float xA = qperm<0x01>(M1);   // sel [1,0,0,0]
        const float xB = qperm<0x1E>(M2);   // sel [2,3,1,0]
        const float sarg = fmaf(W1, xA, fmaf(W2, xB, fmaf(W3, s1, NB)));
        const float e  = fexp2(sarg);
        const float r  = frcp(1.0f + e);
        const float P  = fmaf(pa, s0, pb);
        const float Q  = fmaf(qa, s0, qb);
        const float K  = fmaf(P, r, Q);
        const float s0n = fmaf(a, K, f0);
        const float carg = cs * s0n;        // c-slope uses f[n+1] (same lane)
        const float e2 = fexp2(carg);
        const float r2 = frcp(1.0f + e2);
        const float inner = fmaf(ia, s1, ib);
        const float Kc = fmaf(m2c, r2, inner);
        const float s1n = fmaf(a, Kc, c0);
        s0 = s0n; s1 = s1n;
        acc0 = fmaf(cf, s0, acc0);
        acc1 = fmaf(cf, s1, acc1);
      };
      stage(0.5f, 2.0f);
      stage(0.5f, 4.0f);
      stage(1.0f, 2.0f);
      stage(1.0f, 1.0f);

      // /6 via Newton-refined reciprocal (≈ correctly-rounded division)
      float q0 = acc0 * R6; q0 = fmaf(fmaf(q0, -6.0f, acc0), R6, q0);
      float q1 = acc1 * R6; q1 = fmaf(fmaf(q1, -6.0f, acc1), R6, q1);
      s0 = q0; f0 = q0;
      s1 = q1; c0 = q1;

      *p0 = q0;
      if (dostore1) *p1 = q1;
      p0 += 7 * BATCH;
      p1 += 7 * BATCH;
    }
  }
}

extern "C" void kernel_launch(void* const* d_in, const int* in_sizes, int n_in,
                              void* d_out, int out_size, void* d_ws, size_t ws_size,
                              hipStream_t stream) {
  const float* noise = (const float*)d_in[0];
  const float* gRRe  = (const float*)d_in[1];
  const float* gRWe  = (const float*)d_in[2];
  const float* gWNi  = (const float*)d_in[3];
  const float* gWRi  = (const float*)d_in[4];
  const float* gNRi  = (const float*)d_in[5];
  const float* gNWi  = (const float*)d_in[6];
  float* out = (float*)d_out;

  sleep_rk4_kernel<<<dim3((BATCH * 4) / 64), dim3(64), 0, stream>>>(
      noise, gRRe, gRWe, gWNi, gWRi, gNRi, gNWi, out);
}